// Round 18
// baseline (471.631 us; speedup 1.0000x reference)
//
#include <hip/hip_runtime.h>

typedef unsigned int u32;
typedef unsigned short u16;
typedef short bf16x8 __attribute__((ext_vector_type(8)));
typedef float f32x4 __attribute__((ext_vector_type(4)));
typedef float f32x2 __attribute__((ext_vector_type(2)));
typedef u32 u32x4 __attribute__((ext_vector_type(4)));

#define HBLK 256  // blocks in hist/scatter2 pass

__device__ __forceinline__ u16 f2bf(float f) {
  u32 u = __float_as_uint(f);
  u = (u + 0x7FFFu + ((u >> 16) & 1u)) >> 16;
  return (u16)u;
}
__device__ __forceinline__ float bf2f(u32 h) { return __uint_as_float(h << 16); }

// ---------------- CSR build: bucket sort by dst ----------------
__global__ void hist_wprep_kernel(const int* __restrict__ dst, int* __restrict__ boff,
                                  int* __restrict__ btotal, int E, int nbuk, int chunk,
                                  const float* __restrict__ W2l, const float* __restrict__ W2r,
                                  const float* __restrict__ W3l, const float* __restrict__ W3r,
                                  u16* __restrict__ wt2, u16* __restrict__ wt3,
                                  float* __restrict__ pooled, int* __restrict__ gcnt) {
  int idx = blockIdx.x * 256 + threadIdx.x;
  {
    int which = idx >> 15, r = idx & 32767;
    int j = r >> 8, k = r & 255;
    if (which == 0) {
      float v = (k < 128) ? W2l[k * 128 + j] : W2r[(k - 128) * 128 + j];
      wt2[r] = f2bf(v);
    } else {
      float v = (k < 128) ? W3l[k * 128 + j] : W3r[(k - 128) * 128 + j];
      wt3[r] = f2bf(v);
    }
    if (idx < 8192) pooled[idx] = 0.f;
    if (idx < 64) gcnt[idx] = 0;
  }
  __shared__ int h[1024];
  for (int i = threadIdx.x; i < nbuk; i += 256) h[i] = 0;
  __syncthreads();
  int b0 = blockIdx.x * chunk, b1 = min(b0 + chunk, E);
  for (int e = b0 + threadIdx.x; e < b1; e += 256)
    atomicAdd(&h[dst[e] >> 7], 1);
  __syncthreads();
  for (int i = threadIdx.x; i < nbuk; i += 256)
    boff[i * HBLK + blockIdx.x] = atomicAdd(&btotal[i], h[i]);
}

__global__ void scatter2_kernel(const int* __restrict__ src, const int* __restrict__ dst,
                                const int* __restrict__ btotal, const int* __restrict__ boff,
                                u32* __restrict__ part, int* __restrict__ bbase,
                                int E, int nbuk, int chunk) {
  __shared__ int bt[1024];
  __shared__ int wsum[256];
  __shared__ int cur[1024];
  int tid = threadIdx.x;
  int t4 = tid * 4;
  int v0 = (t4 + 0 < nbuk) ? btotal[t4 + 0] : 0;
  int v1 = (t4 + 1 < nbuk) ? btotal[t4 + 1] : 0;
  int v2 = (t4 + 2 < nbuk) ? btotal[t4 + 2] : 0;
  int v3 = (t4 + 3 < nbuk) ? btotal[t4 + 3] : 0;
  int sum = v0 + v1 + v2 + v3;
  wsum[tid] = sum;
  __syncthreads();
  for (int off = 1; off < 256; off <<= 1) {
    int t = (tid >= off) ? wsum[tid - off] : 0;
    __syncthreads();
    wsum[tid] += t;
    __syncthreads();
  }
  int excl = wsum[tid] - sum;
  bt[t4 + 0] = excl;
  bt[t4 + 1] = excl + v0;
  bt[t4 + 2] = excl + v0 + v1;
  bt[t4 + 3] = excl + v0 + v1 + v2;
  __syncthreads();
  for (int i = tid; i < nbuk; i += 256) {
    cur[i] = bt[i] + boff[i * HBLK + blockIdx.x];
    if (blockIdx.x == 0) bbase[i] = bt[i];
  }
  __syncthreads();
  int b0 = blockIdx.x * chunk, b1 = min(b0 + chunk, E);
  for (int e = b0 + tid; e < b1; e += 256) {
    int d = dst[e];
    int pos = atomicAdd(&cur[d >> 7], 1);
    part[pos] = (u32)src[e] | ((u32)(d & 127) << 25);
  }
}

__global__ void scatter3_kernel(const u32* __restrict__ part, const int* __restrict__ bbase,
                                const float* __restrict__ x,
                                const float* __restrict__ W1l, const float* __restrict__ W1r,
                                const float* __restrict__ b1,
                                int* __restrict__ roff, int* __restrict__ csr,
                                u32* __restrict__ h1, int E, int nbuk, int n) {
  int b = blockIdx.x;
  int tid = threadIdx.x;
  int base = bbase[b];
  int end = (b + 1 < nbuk) ? bbase[b + 1] : E;
  __shared__ int cnt[128];
  __shared__ int s[128];
  __shared__ int cur[128];
  __shared__ float xsum[128];
  __shared__ float meanv[128];
  __shared__ float wlA[128], wrA[128], bA[128];
  if (tid < 128) {
    cnt[tid] = 0; xsum[tid] = 0.f;
    wlA[tid] = W1l[tid]; wrA[tid] = W1r[tid]; bA[tid] = b1[tid];
  }
  __syncthreads();
  for (int e = base + tid; e < end; e += 256)
    atomicAdd(&cnt[part[e] >> 25], 1);
  __syncthreads();
  if (tid < 128) s[tid] = cnt[tid];
  __syncthreads();
  for (int off = 1; off < 128; off <<= 1) {
    int t = (tid >= off && tid < 128) ? s[tid - off] : 0;
    __syncthreads();
    if (tid < 128) s[tid] += t;
    __syncthreads();
  }
  if (tid < 128) {
    int excl = s[tid] - cnt[tid];
    cur[tid] = base + excl;
    int node = b * 128 + tid;
    if (node < n) roff[node] = base + excl;
  }
  if (b == 0 && tid == 0) roff[n] = E;
  __syncthreads();
  for (int e = base + tid; e < end; e += 256) {
    u32 p = part[e];
    int sidx = (int)(p & 0x1FFFFFFu);
    int pos = atomicAdd(&cur[p >> 25], 1);
    csr[pos] = sidx;
    atomicAdd(&xsum[p >> 25], x[sidx]);
  }
  __syncthreads();
  if (tid < 128) meanv[tid] = xsum[tid] / (float)max(cnt[tid], 1);
  __syncthreads();
  int nlocal = min(128, n - b * 128);
  for (int q = tid; q < nlocal * 64; q += 256) {
    int ln = q >> 6, w = q & 63;
    int node = b * 128 + ln;
    int j0 = w * 2;
    float m = meanv[ln], xs = x[node];
    float v0 = fmaxf(m * wlA[j0] + xs * wrA[j0] + bA[j0], 0.f);
    float v1 = fmaxf(m * wlA[j0 + 1] + xs * wrA[j0 + 1] + bA[j0 + 1], 0.f);
    h1[(size_t)node * 64 + w] = (u32)f2bf(v0) | ((u32)f2bf(v1) << 16);
  }
}

// ---------------- fused agg + MFMA layer ----------------
// h_out = relu([mean_agg(h_in) | h_in] @ Wt + b)
// 1024-thread block = 16 waves = 16 rows, ONE ROW PER WAVE (preserves the
// standalone agg's gather parallelism — the R6 failure mode was 16 rows/wave).
// Weights prefetched into regs BEFORE the gather (latency hidden), staged to
// 32 KB LDS in two K-phases (indexing verbatim from correctness-verified R15).
// Means go through LDS (stride 136, verified R6 pattern); waves 0-7 each run
// one 16x16 j-tile (8 MFMAs); coalesced LDS-staged writeback (R16 pattern).
// Out-of-place: reads hin, writes out (no RW aliasing).
__launch_bounds__(1024)
__global__ void aggmm_kernel(const int* __restrict__ csr, const int* __restrict__ roff,
                             const u32* __restrict__ hin, const u16* __restrict__ Wt,
                             const float* __restrict__ bias, u16* __restrict__ out, int n) {
  __shared__ u16 wlds[16384];    // 32 KB weight phase
  __shared__ u16 clds[16 * 136]; // mean rows -> C rows (4.25 KB, 2-way-free banks)
  int wave = threadIdx.x >> 6, lane = threadIdx.x & 63;
  int grp = lane >> 4, li = lane & 15;
  int quad = grp, l16 = li;
  int row0 = blockIdx.x * 16;
  int i = row0 + wave;
  // --- prefetch both weight phases into regs (hidden under gather latency) ---
  int c0 = threadIdx.x, c1 = threadIdx.x + 1024;
  int j0 = c0 >> 4, ch0 = c0 & 15;
  int j1 = c1 >> 4, ch1 = c1 & 15;
  u32x4 w0a = *(const u32x4*)(&Wt[j0 * 256 + ch0 * 8]);
  u32x4 w0b = *(const u32x4*)(&Wt[j1 * 256 + ch1 * 8]);
  u32x4 w1a = *(const u32x4*)(&Wt[j0 * 256 + (16 + ch0) * 8]);
  u32x4 w1b = *(const u32x4*)(&Wt[j1 * 256 + (16 + ch1) * 8]);
  // --- aggregation: one row per wave, 4x16-lane groups, 16 edges in flight ---
  f32x2 a[4] = {};
  int e0 = 0, e1 = 0;
  if (i < n) { e0 = roff[i]; e1 = roff[i + 1]; }
  int e = e0 + grp;
  for (; e + 12 < e1; e += 16) {
    int s0 = csr[e], s1 = csr[e + 4], s2 = csr[e + 8], s3 = csr[e + 12];
    u32x4 v0 = *(const u32x4*)(hin + (size_t)s0 * 64 + li * 4);
    u32x4 v1 = *(const u32x4*)(hin + (size_t)s1 * 64 + li * 4);
    u32x4 v2 = *(const u32x4*)(hin + (size_t)s2 * 64 + li * 4);
    u32x4 v3 = *(const u32x4*)(hin + (size_t)s3 * 64 + li * 4);
#pragma unroll
    for (int w = 0; w < 4; ++w) {
      a[w] += (f32x2){bf2f(v0[w] & 0xFFFFu), bf2f(v0[w] >> 16)};
      a[w] += (f32x2){bf2f(v1[w] & 0xFFFFu), bf2f(v1[w] >> 16)};
      a[w] += (f32x2){bf2f(v2[w] & 0xFFFFu), bf2f(v2[w] >> 16)};
      a[w] += (f32x2){bf2f(v3[w] & 0xFFFFu), bf2f(v3[w] >> 16)};
    }
  }
  for (; e + 4 < e1; e += 8) {
    int s0 = csr[e], s1 = csr[e + 4];
    u32x4 v0 = *(const u32x4*)(hin + (size_t)s0 * 64 + li * 4);
    u32x4 v1 = *(const u32x4*)(hin + (size_t)s1 * 64 + li * 4);
#pragma unroll
    for (int w = 0; w < 4; ++w) {
      a[w] += (f32x2){bf2f(v0[w] & 0xFFFFu), bf2f(v0[w] >> 16)};
      a[w] += (f32x2){bf2f(v1[w] & 0xFFFFu), bf2f(v1[w] >> 16)};
    }
  }
  if (e < e1) {
    int s0 = csr[e];
    u32x4 v0 = *(const u32x4*)(hin + (size_t)s0 * 64 + li * 4);
#pragma unroll
    for (int w = 0; w < 4; ++w)
      a[w] += (f32x2){bf2f(v0[w] & 0xFFFFu), bf2f(v0[w] >> 16)};
  }
#pragma unroll
  for (int w = 0; w < 4; ++w) {
    a[w].x += __shfl_xor(a[w].x, 16, 64);
    a[w].y += __shfl_xor(a[w].y, 16, 64);
    a[w].x += __shfl_xor(a[w].x, 32, 64);
    a[w].y += __shfl_xor(a[w].y, 32, 64);
  }
  if (grp == 0) {
    float inv = 1.f / (float)max(e1 - e0, 1);
    u32x4 o;
#pragma unroll
    for (int w = 0; w < 4; ++w)
      o[w] = (u32)f2bf(a[w].x * inv) | ((u32)f2bf(a[w].y * inv) << 16);
    *(u32x4*)(&clds[wave * 136 + li * 8]) = o;  // zeros if i >= n
  }
  // --- stage phase-0 weights from regs ---
  *(u32x4*)(&wlds[j0 * 128 + (ch0 ^ (j0 & 15)) * 8]) = w0a;
  *(u32x4*)(&wlds[j1 * 128 + (ch1 ^ (j1 & 15)) * 8]) = w0b;
  __syncthreads();
  // --- MFMA phase 0: A = means (LDS), waves 0..7 own j-tile = wave ---
  int mm = row0 + l16;
  int mc = mm < n ? mm : (n - 1);
  f32x4 acc = {};
  if (wave < 8) {
#pragma unroll
    for (int s = 0; s < 4; ++s) {
      bf16x8 af = *(const bf16x8*)(&clds[l16 * 136 + s * 32 + quad * 8]);
      int cc = (s << 2) + quad;
      int swz = cc ^ l16;
      bf16x8 b = *(const bf16x8*)(&wlds[(wave * 16 + l16) * 128 + swz * 8]);
      acc = __builtin_amdgcn_mfma_f32_16x16x32_bf16(af, b, acc, 0, 0, 0);
    }
  }
  __syncthreads();
  // --- stage phase-1 weights ---
  *(u32x4*)(&wlds[j0 * 128 + (ch0 ^ (j0 & 15)) * 8]) = w1a;
  *(u32x4*)(&wlds[j1 * 128 + (ch1 ^ (j1 & 15)) * 8]) = w1b;
  __syncthreads();
  // --- MFMA phase 1: A = self rows (global, L2-hot) ---
  if (wave < 8) {
    const u16* A = (const u16*)hin + (size_t)mc * 128;
#pragma unroll
    for (int s = 0; s < 4; ++s) {
      bf16x8 af = *(const bf16x8*)(A + s * 32 + quad * 8);
      int cc = (s << 2) + quad;
      int swz = cc ^ l16;
      bf16x8 b = *(const bf16x8*)(&wlds[(wave * 16 + l16) * 128 + swz * 8]);
      acc = __builtin_amdgcn_mfma_f32_16x16x32_bf16(af, b, acc, 0, 0, 0);
    }
  }
  __syncthreads();
  // --- epilogue: bias+relu+bf16 -> clds (C layout: col=lane&15, row=quad*4+r) ---
  if (wave < 8) {
    int j = wave * 16 + l16;
    float bj = bias[j];
#pragma unroll
    for (int r = 0; r < 4; ++r) {
      float v = acc[r] + bj;
      clds[(quad * 4 + r) * 136 + j] = f2bf(fmaxf(v, 0.f));
    }
  }
  __syncthreads();
  // --- coalesced writeback: 16 rows x 16 chunks of 16B ---
  if (threadIdx.x < 256) {
    int rl = threadIdx.x >> 4, ch = threadIdx.x & 15;
    int mr = row0 + rl;
    if (mr < n)
      *(u32x4*)(&out[(size_t)mr * 128 + ch * 8]) =
          *(const u32x4*)(&clds[rl * 136 + ch * 8]);
  }
}

// ---------------- pooling (LDS-staged batch ids, 4 rows in flight) ----------------
#define PB_NODES 128
__global__ void pool_partial(const int* __restrict__ batch, const u32* __restrict__ h3,
                             float* __restrict__ pooled, int* __restrict__ gcnt, int n) {
  __shared__ int bg[PB_NODES];
  int tid = threadIdx.x;
  int start = blockIdx.x * PB_NODES;
  int cntN = min(PB_NODES, n - start);
  if (tid < cntN) bg[tid] = batch[start + tid];
  __syncthreads();
  int wave = tid >> 6, lane = tid & 63;
  float a0 = 0.f, a1 = 0.f;
  int gcur = -1, cnt = 0;
  int k = wave;
  for (; k + 12 < cntN; k += 16) {
    u32 v0 = h3[(size_t)(start + k) * 64 + lane];
    u32 v1 = h3[(size_t)(start + k + 4) * 64 + lane];
    u32 v2 = h3[(size_t)(start + k + 8) * 64 + lane];
    u32 v3 = h3[(size_t)(start + k + 12) * 64 + lane];
    int g0 = bg[k], g1 = bg[k + 4], g2 = bg[k + 8], g3 = bg[k + 12];
    u32 vv[4] = {v0, v1, v2, v3};
    int gg[4] = {g0, g1, g2, g3};
#pragma unroll
    for (int q = 0; q < 4; ++q) {
      if (gg[q] != gcur) {
        if (gcur >= 0) {
          atomicAdd(&pooled[gcur * 128 + lane * 2], a0);
          atomicAdd(&pooled[gcur * 128 + lane * 2 + 1], a1);
          if (lane == 0) atomicAdd(&gcnt[gcur], cnt);
        }
        gcur = gg[q]; a0 = 0.f; a1 = 0.f; cnt = 0;
      }
      a0 += bf2f(vv[q] & 0xFFFFu);
      a1 += bf2f(vv[q] >> 16);
      cnt++;
    }
  }
  for (; k < cntN; k += 4) {
    u32 v = h3[(size_t)(start + k) * 64 + lane];
    int g = bg[k];
    if (g != gcur) {
      if (gcur >= 0) {
        atomicAdd(&pooled[gcur * 128 + lane * 2], a0);
        atomicAdd(&pooled[gcur * 128 + lane * 2 + 1], a1);
        if (lane == 0) atomicAdd(&gcnt[gcur], cnt);
      }
      gcur = g; a0 = 0.f; a1 = 0.f; cnt = 0;
    }
    a0 += bf2f(v & 0xFFFFu);
    a1 += bf2f(v >> 16);
    cnt++;
  }
  if (gcur >= 0) {
    atomicAdd(&pooled[gcur * 128 + lane * 2], a0);
    atomicAdd(&pooled[gcur * 128 + lane * 2 + 1], a1);
    if (lane == 0) atomicAdd(&gcnt[gcur], cnt);
  }
}

__global__ void head_kernel(const float* __restrict__ pooled, const int* __restrict__ gcnt,
                            const float* __restrict__ Wfc, const float* __restrict__ bfc,
                            float* __restrict__ out) {
  __shared__ float lg[64][10];
  int t = threadIdx.x;
  if (t < 640) {
    int g = t / 10, c = t % 10;
    float inv = 1.f / (float)max(gcnt[g], 1);
    float acc = bfc[c];
    for (int k = 0; k < 128; ++k) acc += pooled[g * 128 + k] * inv * Wfc[k * 10 + c];
    lg[g][c] = acc;
  }
  __syncthreads();
  if (t < 640) {
    int g = t / 10, c = t % 10;
    float mx = -1e30f;
    for (int q = 0; q < 10; ++q) mx = fmaxf(mx, lg[g][q]);
    float se = 0.f;
    for (int q = 0; q < 10; ++q) se += expf(lg[g][q] - mx);
    out[g * 10 + c] = lg[g][c] - mx - logf(se);
  }
}

extern "C" void kernel_launch(void* const* d_in, const int* in_sizes, int n_in,
                              void* d_out, int out_size, void* d_ws, size_t ws_size,
                              hipStream_t stream) {
  const float* x   = (const float*)d_in[0];
  const int* ei    = (const int*)d_in[1];
  const int* batch = (const int*)d_in[2];
  const float* W1l = (const float*)d_in[3];
  const float* W1r = (const float*)d_in[4];
  const float* b1  = (const float*)d_in[5];
  const float* W2l = (const float*)d_in[6];
  const float* W2r = (const float*)d_in[7];
  const float* b2  = (const float*)d_in[8];
  const float* W3l = (const float*)d_in[9];
  const float* W3r = (const float*)d_in[10];
  const float* b3  = (const float*)d_in[11];
  const float* Wfc = (const float*)d_in[12];
  const float* bfc = (const float*)d_in[13];
  float* out = (float*)d_out;
  int N = in_sizes[0];
  int E = in_sizes[1] / 2;
  const int* src = ei;
  const int* dst = ei + E;

  char* p = (char*)d_ws;
  auto alloc = [&](size_t bytes) { void* r = (void*)p; p += (bytes + 255) & ~(size_t)255; return r; };
  int* roff   = (int*)alloc((size_t)(N + 1) * 4);
  int* csr    = (int*)alloc((size_t)E * 4);
  u32* bufA   = (u32*)alloc((size_t)N * 64 * 4);  // h1 -> h3 (aliases boff early)
  u32* bufB   = (u32*)alloc((size_t)N * 64 * 4);  // h2       (aliases part early)
  u16* wt2    = (u16*)alloc(32768 * 2);
  u16* wt3    = (u16*)alloc(32768 * 2);
  float* pooled = (float*)alloc(64 * 128 * 4);
  int* gcnt   = (int*)alloc(64 * 4);
  int* btotal = (int*)alloc(1024 * 4);
  int* bbase  = (int*)alloc(1024 * 4);

  int nbuk = (N + 127) >> 7;          // 782
  int* boff = (int*)bufA;             // nbuk*HBLK ints = 800 KB
  u32* part = (u32*)bufB;             // E u32 = 6.4 MB
  int chunk = (E + HBLK - 1) / HBLK;  // 6250

  hipMemsetAsync(btotal, 0, 1024 * 4, stream);
  hist_wprep_kernel<<<HBLK, 256, 0, stream>>>(dst, boff, btotal, E, nbuk, chunk,
                                              W2l, W2r, W3l, W3r, wt2, wt3,
                                              pooled, gcnt);
  scatter2_kernel<<<HBLK, 256, 0, stream>>>(src, dst, btotal, boff, part, bbase,
                                            E, nbuk, chunk);
  scatter3_kernel<<<nbuk, 256, 0, stream>>>(part, bbase, x, W1l, W1r, b1,
                                            roff, csr, bufA, E, nbuk, N);
  aggmm_kernel<<<(N + 15) / 16, 1024, 0, stream>>>(csr, roff, bufA, wt2, b2,
                                                   (u16*)bufB, N);  // h2 = layer2(h1)
  aggmm_kernel<<<(N + 15) / 16, 1024, 0, stream>>>(csr, roff, bufB, wt3, b3,
                                                   (u16*)bufA, N);  // h3 = layer3(h2)
  pool_partial<<<(N + PB_NODES - 1) / PB_NODES, 256, 0, stream>>>(batch, bufA, pooled, gcnt, N);
  head_kernel<<<1, 640, 0, stream>>>(pooled, gcnt, Wfc, bfc, out);
}

// Round 19
// 330.812 us; speedup vs baseline: 1.4257x; 1.4257x over previous
//
#include <hip/hip_runtime.h>

typedef unsigned int u32;
typedef unsigned short u16;
typedef short bf16x8 __attribute__((ext_vector_type(8)));
typedef float f32x4 __attribute__((ext_vector_type(4)));
typedef float f32x2 __attribute__((ext_vector_type(2)));
typedef u32 u32x4 __attribute__((ext_vector_type(4)));

#define HBLK 256  // blocks in hist/scatter2 pass

__device__ __forceinline__ u16 f2bf(float f) {
  u32 u = __float_as_uint(f);
  u = (u + 0x7FFFu + ((u >> 16) & 1u)) >> 16;
  return (u16)u;
}
__device__ __forceinline__ float bf2f(u32 h) { return __uint_as_float(h << 16); }

// ---------------- CSR build: bucket sort by dst ----------------
// bucket = dst >> 7 (128 nodes per bucket).
// Per-block bucket counts taken via atomicAdd on btotal -> return value is this
// block's intra-bucket offset (boff). No 200k scan needed.
// Fused: weight packing + pooled/gcnt zeroing.
__global__ void hist_wprep_kernel(const int* __restrict__ dst, int* __restrict__ boff,
                                  int* __restrict__ btotal, int E, int nbuk, int chunk,
                                  const float* __restrict__ W2l, const float* __restrict__ W2r,
                                  const float* __restrict__ W3l, const float* __restrict__ W3r,
                                  u16* __restrict__ wt2, u16* __restrict__ wt3,
                                  float* __restrict__ pooled, int* __restrict__ gcnt) {
  // --- wprep part (independent; exactly 256 blocks x 256 threads = 65536 idx) ---
  int idx = blockIdx.x * 256 + threadIdx.x;
  {
    int which = idx >> 15, r = idx & 32767;
    int j = r >> 8, k = r & 255;
    if (which == 0) {
      float v = (k < 128) ? W2l[k * 128 + j] : W2r[(k - 128) * 128 + j];
      wt2[r] = f2bf(v);
    } else {
      float v = (k < 128) ? W3l[k * 128 + j] : W3r[(k - 128) * 128 + j];
      wt3[r] = f2bf(v);
    }
    if (idx < 8192) pooled[idx] = 0.f;
    if (idx < 64) gcnt[idx] = 0;
  }
  // --- hist part ---
  __shared__ int h[1024];
  for (int i = threadIdx.x; i < nbuk; i += 256) h[i] = 0;
  __syncthreads();
  int b0 = blockIdx.x * chunk, b1 = min(b0 + chunk, E);
  for (int e = b0 + threadIdx.x; e < b1; e += 256)
    atomicAdd(&h[dst[e] >> 7], 1);
  __syncthreads();
  for (int i = threadIdx.x; i < nbuk; i += 256)
    boff[i * HBLK + blockIdx.x] = atomicAdd(&btotal[i], h[i]);
}

// partition edges into bucket-ordered part[]: packed (dstLow7<<25 | src).
// Bucket bases computed by an inline LDS scan of btotal (782 entries, ~3KB).
__global__ void scatter2_kernel(const int* __restrict__ src, const int* __restrict__ dst,
                                const int* __restrict__ btotal, const int* __restrict__ boff,
                                u32* __restrict__ part, int* __restrict__ bbase,
                                int E, int nbuk, int chunk) {
  __shared__ int bt[1024];
  __shared__ int wsum[256];
  __shared__ int cur[1024];
  int tid = threadIdx.x;
  // load 4 entries/thread, sequential local prefix + Hillis-Steele over thread sums
  int t4 = tid * 4;
  int v0 = (t4 + 0 < nbuk) ? btotal[t4 + 0] : 0;
  int v1 = (t4 + 1 < nbuk) ? btotal[t4 + 1] : 0;
  int v2 = (t4 + 2 < nbuk) ? btotal[t4 + 2] : 0;
  int v3 = (t4 + 3 < nbuk) ? btotal[t4 + 3] : 0;
  int sum = v0 + v1 + v2 + v3;
  wsum[tid] = sum;
  __syncthreads();
  for (int off = 1; off < 256; off <<= 1) {
    int t = (tid >= off) ? wsum[tid - off] : 0;
    __syncthreads();
    wsum[tid] += t;
    __syncthreads();
  }
  int excl = wsum[tid] - sum;
  bt[t4 + 0] = excl;
  bt[t4 + 1] = excl + v0;
  bt[t4 + 2] = excl + v0 + v1;
  bt[t4 + 3] = excl + v0 + v1 + v2;
  __syncthreads();
  for (int i = tid; i < nbuk; i += 256) {
    cur[i] = bt[i] + boff[i * HBLK + blockIdx.x];
    if (blockIdx.x == 0) bbase[i] = bt[i];  // publish for scatter3
  }
  __syncthreads();
  int b0 = blockIdx.x * chunk, b1 = min(b0 + chunk, E);
  for (int e = b0 + tid; e < b1; e += 256) {
    int d = dst[e];
    int pos = atomicAdd(&cur[d >> 7], 1);
    part[pos] = (u32)src[e] | ((u32)(d & 127) << 25);
  }
}

// per-bucket: count per node, scan -> roff, scatter src into contiguous csr window,
// accumulate x[src] -> mean, then compute h1 rows for this bucket (fused layer 1).
__global__ void scatter3_kernel(const u32* __restrict__ part, const int* __restrict__ bbase,
                                const float* __restrict__ x,
                                const float* __restrict__ W1l, const float* __restrict__ W1r,
                                const float* __restrict__ b1,
                                int* __restrict__ roff, int* __restrict__ csr,
                                u32* __restrict__ h1, int E, int nbuk, int n) {
  int b = blockIdx.x;
  int tid = threadIdx.x;
  int base = bbase[b];
  int end = (b + 1 < nbuk) ? bbase[b + 1] : E;
  __shared__ int cnt[128];
  __shared__ int s[128];
  __shared__ int cur[128];
  __shared__ float xsum[128];
  __shared__ float meanv[128];
  __shared__ float wlA[128], wrA[128], bA[128];
  if (tid < 128) {
    cnt[tid] = 0; xsum[tid] = 0.f;
    wlA[tid] = W1l[tid]; wrA[tid] = W1r[tid]; bA[tid] = b1[tid];
  }
  __syncthreads();
  for (int e = base + tid; e < end; e += 256)
    atomicAdd(&cnt[part[e] >> 25], 1);
  __syncthreads();
  if (tid < 128) s[tid] = cnt[tid];
  __syncthreads();
  for (int off = 1; off < 128; off <<= 1) {
    int t = (tid >= off && tid < 128) ? s[tid - off] : 0;
    __syncthreads();
    if (tid < 128) s[tid] += t;
    __syncthreads();
  }
  if (tid < 128) {
    int excl = s[tid] - cnt[tid];
    cur[tid] = base + excl;
    int node = b * 128 + tid;
    if (node < n) roff[node] = base + excl;
  }
  if (b == 0 && tid == 0) roff[n] = E;
  __syncthreads();
  for (int e = base + tid; e < end; e += 256) {
    u32 p = part[e];
    int sidx = (int)(p & 0x1FFFFFFu);
    int pos = atomicAdd(&cur[p >> 25], 1);
    csr[pos] = sidx;
    atomicAdd(&xsum[p >> 25], x[sidx]);
  }
  __syncthreads();
  if (tid < 128) meanv[tid] = xsum[tid] / (float)max(cnt[tid], 1);
  __syncthreads();
  // fused layer-1: h1[node][j] = relu(mean*W1l[j] + x[node]*W1r[j] + b1[j]), bf16-packed
  int nlocal = min(128, n - b * 128);
  for (int q = tid; q < nlocal * 64; q += 256) {
    int ln = q >> 6, w = q & 63;
    int node = b * 128 + ln;
    int j0 = w * 2;
    float m = meanv[ln], xs = x[node];
    float v0 = fmaxf(m * wlA[j0] + xs * wrA[j0] + bA[j0], 0.f);
    float v1 = fmaxf(m * wlA[j0 + 1] + xs * wrA[j0 + 1] + bA[j0 + 1], 0.f);
    h1[(size_t)node * 64 + w] = (u32)f2bf(v0) | ((u32)f2bf(v1) << 16);
  }
}

// generic mean-aggregation of bf16 feature rows over CSR.
// 4x16-lane groups each gather a different edge's 256B row via dwordx4;
// 16 edges in flight per wave.
__global__ void agg_kernel(const int* __restrict__ csr, const int* __restrict__ roff,
                           const u32* __restrict__ hin, u32* __restrict__ outv, int n) {
  int wave = threadIdx.x >> 6, lane = threadIdx.x & 63;
  int i = blockIdx.x * 4 + wave;
  if (i >= n) return;
  int grp = lane >> 4, li = lane & 15;
  int e0 = roff[i], e1 = roff[i + 1];
  f32x2 a[4] = {};
  int e = e0 + grp;
  for (; e + 12 < e1; e += 16) {
    int s0 = csr[e], s1 = csr[e + 4], s2 = csr[e + 8], s3 = csr[e + 12];
    u32x4 v0 = *(const u32x4*)(hin + (size_t)s0 * 64 + li * 4);
    u32x4 v1 = *(const u32x4*)(hin + (size_t)s1 * 64 + li * 4);
    u32x4 v2 = *(const u32x4*)(hin + (size_t)s2 * 64 + li * 4);
    u32x4 v3 = *(const u32x4*)(hin + (size_t)s3 * 64 + li * 4);
#pragma unroll
    for (int w = 0; w < 4; ++w) {
      a[w] += (f32x2){bf2f(v0[w] & 0xFFFFu), bf2f(v0[w] >> 16)};
      a[w] += (f32x2){bf2f(v1[w] & 0xFFFFu), bf2f(v1[w] >> 16)};
      a[w] += (f32x2){bf2f(v2[w] & 0xFFFFu), bf2f(v2[w] >> 16)};
      a[w] += (f32x2){bf2f(v3[w] & 0xFFFFu), bf2f(v3[w] >> 16)};
    }
  }
  for (; e + 4 < e1; e += 8) {
    int s0 = csr[e], s1 = csr[e + 4];
    u32x4 v0 = *(const u32x4*)(hin + (size_t)s0 * 64 + li * 4);
    u32x4 v1 = *(const u32x4*)(hin + (size_t)s1 * 64 + li * 4);
#pragma unroll
    for (int w = 0; w < 4; ++w) {
      a[w] += (f32x2){bf2f(v0[w] & 0xFFFFu), bf2f(v0[w] >> 16)};
      a[w] += (f32x2){bf2f(v1[w] & 0xFFFFu), bf2f(v1[w] >> 16)};
    }
  }
  if (e < e1) {
    int s0 = csr[e];
    u32x4 v0 = *(const u32x4*)(hin + (size_t)s0 * 64 + li * 4);
#pragma unroll
    for (int w = 0; w < 4; ++w)
      a[w] += (f32x2){bf2f(v0[w] & 0xFFFFu), bf2f(v0[w] >> 16)};
  }
#pragma unroll
  for (int w = 0; w < 4; ++w) {
    a[w].x += __shfl_xor(a[w].x, 16, 64);
    a[w].y += __shfl_xor(a[w].y, 16, 64);
    a[w].x += __shfl_xor(a[w].x, 32, 64);
    a[w].y += __shfl_xor(a[w].y, 32, 64);
  }
  if (grp == 0) {
    float inv = 1.f / (float)max(e1 - e0, 1);
    u32x4 o;
#pragma unroll
    for (int w = 0; w < 4; ++w)
      o[w] = (u32)f2bf(a[w].x * inv) | ((u32)f2bf(a[w].y * inv) << 16);
    *(u32x4*)(outv + (size_t)i * 64 + li * 4) = o;
  }
}

// h_next = relu([mean | h] @ [Wl; Wr] + b), MFMA 16x16x32 bf16.
// Weights staged in LDS (XOR-swizzled, conflict-free ds_read_b128).
// Epilogue: C staged into the (now dead) weight LDS with padded row stride
// (136 u16 -> <=2-way bank aliasing), then written back with fully-coalesced
// dwordx4 stores. (R16: fixed 27% write amplification, best measured variant.)
__launch_bounds__(512)
__global__ void mm_kernel(const u16* Aleft, const u16* Aright,
                          const u16* __restrict__ Wt, const float* __restrict__ bias,
                          u16* Out, int n) {
  __shared__ u16 wlds[32768];  // 64 KB: weights, then reused for C staging
  for (int c = threadIdx.x; c < 4096; c += 512) {
    int j = c >> 5, ch = c & 31;
    int swz = ch ^ (j & 31);
    *(u32x4*)(&wlds[j * 256 + swz * 8]) = *(const u32x4*)(&Wt[j * 256 + ch * 8]);
  }
  __syncthreads();
  int wave = threadIdx.x >> 6;
  int lane = threadIdx.x & 63;
  int quad = lane >> 4, l16 = lane & 15;
  int row0 = blockIdx.x * 128 + wave * 16;
  int m = row0 + l16;
  int mc = m < n ? m : (n - 1);
  f32x4 acc[8] = {};
  const u16* Ah[2] = {Aleft, Aright};
#pragma unroll
  for (int half = 0; half < 2; ++half) {
    const u16* A = Ah[half] + (size_t)mc * 128;
#pragma unroll
    for (int s = 0; s < 4; ++s) {
      bf16x8 a = *(const bf16x8*)(A + s * 32 + quad * 8);  // A[m][k], k = s*32+quad*8+j
      int chunk = (half << 4) + (s << 2) + quad;
#pragma unroll
      for (int t = 0; t < 8; ++t) {
        int j = t * 16 + l16;
        int swz = chunk ^ (j & 31);
        bf16x8 b = *(const bf16x8*)(&wlds[j * 256 + swz * 8]);  // B[k][j] = Wt[j][k]
        acc[t] = __builtin_amdgcn_mfma_f32_16x16x32_bf16(a, b, acc[t], 0, 0, 0);
      }
    }
  }
  // C layout: col = lane&15, row = quad*4 + reg (m89-verified)
  // ---- epilogue: bias+relu+bf16 -> LDS staging (stride 136 u16) ----
  __syncthreads();  // all weight reads done; wlds reusable
  int rl_base = wave * 16 + quad * 4;  // local row base of this lane's outputs
#pragma unroll
  for (int t = 0; t < 8; ++t) {
    int j = t * 16 + l16;
    float bj = bias[j];
#pragma unroll
    for (int r = 0; r < 4; ++r) {
      float v = acc[t][r] + bj;
      wlds[(rl_base + r) * 136 + j] = f2bf(fmaxf(v, 0.f));
    }
  }
  __syncthreads();
  // ---- coalesced write-back: 128 rows x 16 chunks of 16B, 4 rounds ----
  int base_row = blockIdx.x * 128;
  for (int q = 0; q < 4; ++q) {
    int idx = q * 512 + threadIdx.x;  // 0..2047
    int rl = idx >> 4;                // 0..127
    int ch = idx & 15;                // 16B chunk within 256B row
    int mr = base_row + rl;
    if (mr < n)
      *(u32x4*)(&Out[(size_t)mr * 128 + ch * 8]) =
          *(const u32x4*)(&wlds[rl * 136 + ch * 8]);
  }
}

// ---------------- pooling (MLP version: LDS-staged batch ids, 4 rows in flight) ----------------
#define PB_NODES 128
__global__ void pool_partial(const int* __restrict__ batch, const u32* __restrict__ h3,
                             float* __restrict__ pooled, int* __restrict__ gcnt, int n) {
  __shared__ int bg[PB_NODES];
  int tid = threadIdx.x;
  int start = blockIdx.x * PB_NODES;
  int cntN = min(PB_NODES, n - start);
  if (tid < cntN) bg[tid] = batch[start + tid];
  __syncthreads();
  int wave = tid >> 6, lane = tid & 63;
  float a0 = 0.f, a1 = 0.f;
  int gcur = -1, cnt = 0;
  int k = wave;
  // 4-deep unroll: rows k,k+4,k+8,k+12 loaded before any flush logic
  for (; k + 12 < cntN; k += 16) {
    u32 v0 = h3[(size_t)(start + k) * 64 + lane];
    u32 v1 = h3[(size_t)(start + k + 4) * 64 + lane];
    u32 v2 = h3[(size_t)(start + k + 8) * 64 + lane];
    u32 v3 = h3[(size_t)(start + k + 12) * 64 + lane];
    int g0 = bg[k], g1 = bg[k + 4], g2 = bg[k + 8], g3 = bg[k + 12];
    u32 vv[4] = {v0, v1, v2, v3};
    int gg[4] = {g0, g1, g2, g3};
#pragma unroll
    for (int q = 0; q < 4; ++q) {
      if (gg[q] != gcur) {
        if (gcur >= 0) {
          atomicAdd(&pooled[gcur * 128 + lane * 2], a0);
          atomicAdd(&pooled[gcur * 128 + lane * 2 + 1], a1);
          if (lane == 0) atomicAdd(&gcnt[gcur], cnt);
        }
        gcur = gg[q]; a0 = 0.f; a1 = 0.f; cnt = 0;
      }
      a0 += bf2f(vv[q] & 0xFFFFu);
      a1 += bf2f(vv[q] >> 16);
      cnt++;
    }
  }
  for (; k < cntN; k += 4) {
    u32 v = h3[(size_t)(start + k) * 64 + lane];
    int g = bg[k];
    if (g != gcur) {
      if (gcur >= 0) {
        atomicAdd(&pooled[gcur * 128 + lane * 2], a0);
        atomicAdd(&pooled[gcur * 128 + lane * 2 + 1], a1);
        if (lane == 0) atomicAdd(&gcnt[gcur], cnt);
      }
      gcur = g; a0 = 0.f; a1 = 0.f; cnt = 0;
    }
    a0 += bf2f(v & 0xFFFFu);
    a1 += bf2f(v >> 16);
    cnt++;
  }
  if (gcur >= 0) {
    atomicAdd(&pooled[gcur * 128 + lane * 2], a0);
    atomicAdd(&pooled[gcur * 128 + lane * 2 + 1], a1);
    if (lane == 0) atomicAdd(&gcnt[gcur], cnt);
  }
}

__global__ void head_kernel(const float* __restrict__ pooled, const int* __restrict__ gcnt,
                            const float* __restrict__ Wfc, const float* __restrict__ bfc,
                            float* __restrict__ out) {
  __shared__ float lg[64][10];
  int t = threadIdx.x;
  if (t < 640) {
    int g = t / 10, c = t % 10;
    float inv = 1.f / (float)max(gcnt[g], 1);
    float acc = bfc[c];
    for (int k = 0; k < 128; ++k) acc += pooled[g * 128 + k] * inv * Wfc[k * 10 + c];
    lg[g][c] = acc;
  }
  __syncthreads();
  if (t < 640) {
    int g = t / 10, c = t % 10;
    float mx = -1e30f;
    for (int q = 0; q < 10; ++q) mx = fmaxf(mx, lg[g][q]);
    float se = 0.f;
    for (int q = 0; q < 10; ++q) se += expf(lg[g][q] - mx);
    out[g * 10 + c] = lg[g][c] - mx - logf(se);
  }
}

extern "C" void kernel_launch(void* const* d_in, const int* in_sizes, int n_in,
                              void* d_out, int out_size, void* d_ws, size_t ws_size,
                              hipStream_t stream) {
  const float* x   = (const float*)d_in[0];
  const int* ei    = (const int*)d_in[1];
  const int* batch = (const int*)d_in[2];
  const float* W1l = (const float*)d_in[3];
  const float* W1r = (const float*)d_in[4];
  const float* b1  = (const float*)d_in[5];
  const float* W2l = (const float*)d_in[6];
  const float* W2r = (const float*)d_in[7];
  const float* b2  = (const float*)d_in[8];
  const float* W3l = (const float*)d_in[9];
  const float* W3r = (const float*)d_in[10];
  const float* b3  = (const float*)d_in[11];
  const float* Wfc = (const float*)d_in[12];
  const float* bfc = (const float*)d_in[13];
  float* out = (float*)d_out;
  int N = in_sizes[0];
  int E = in_sizes[1] / 2;
  const int* src = ei;
  const int* dst = ei + E;

  char* p = (char*)d_ws;
  auto alloc = [&](size_t bytes) { void* r = (void*)p; p += (bytes + 255) & ~(size_t)255; return r; };
  int* roff   = (int*)alloc((size_t)(N + 1) * 4);
  int* csr    = (int*)alloc((size_t)E * 4);
  u32* bufA   = (u32*)alloc((size_t)N * 64 * 4);  // h1 -> mean3 -> h3 (aliases boff early)
  u32* bufB   = (u32*)alloc((size_t)N * 64 * 4);  // mean2 -> h2      (aliases part early)
  u16* wt2    = (u16*)alloc(32768 * 2);
  u16* wt3    = (u16*)alloc(32768 * 2);
  float* pooled = (float*)alloc(64 * 128 * 4);
  int* gcnt   = (int*)alloc(64 * 4);
  int* btotal = (int*)alloc(1024 * 4);
  int* bbase  = (int*)alloc(1024 * 4);

  // CSR-build-time aliases (boff read only by scatter2; scatter3 writes h1
  // into bufA but reads only bbase/part/x -> no clobber hazard)
  int nbuk = (N + 127) >> 7;          // 782
  int* boff = (int*)bufA;             // nbuk*HBLK ints = 800 KB
  u32* part = (u32*)bufB;             // E u32 = 6.4 MB
  int chunk = (E + HBLK - 1) / HBLK;  // 6250

  hipMemsetAsync(btotal, 0, 1024 * 4, stream);
  hist_wprep_kernel<<<HBLK, 256, 0, stream>>>(dst, boff, btotal, E, nbuk, chunk,
                                              W2l, W2r, W3l, W3r, wt2, wt3,
                                              pooled, gcnt);
  scatter2_kernel<<<HBLK, 256, 0, stream>>>(src, dst, btotal, boff, part, bbase,
                                            E, nbuk, chunk);
  scatter3_kernel<<<nbuk, 256, 0, stream>>>(part, bbase, x, W1l, W1r, b1,
                                            roff, csr, bufA, E, nbuk, N);
  agg_kernel<<<(N + 3) / 4, 256, 0, stream>>>(csr, roff, bufA, bufB, N);   // mean2 = agg(h1)
  mm_kernel<<<(N + 127) / 128, 512, 0, stream>>>((const u16*)bufB, (const u16*)bufA, wt2, b2,
                                                 (u16*)bufB, N);
  agg_kernel<<<(N + 3) / 4, 256, 0, stream>>>(csr, roff, bufB, bufA, N);   // mean3 = agg(h2)
  mm_kernel<<<(N + 127) / 128, 512, 0, stream>>>((const u16*)bufA, (const u16*)bufB, wt3, b3,
                                                 (u16*)bufA, N);
  pool_partial<<<(N + PB_NODES - 1) / PB_NODES, 256, 0, stream>>>(batch, bufA, pooled, gcnt, N);
  head_kernel<<<1, 640, 0, stream>>>(pooled, gcnt, Wfc, bfc, out);
}